// Round 1
// baseline (86.588 us; speedup 1.0000x reference)
//
#include <hip/hip_runtime.h>

// Plenoxels: trilinear voxel interpolation (192^3 x 28 channels) + SH deg-2 eval.
// Key optimization: ~84% of points fail the |x/1.5|<0.5 mask -> skip gather entirely.

#define VNL 192

__global__ __launch_bounds__(256) void plenoxels_kernel(
    const float* __restrict__ x,
    const float* __restrict__ d,
    const float* __restrict__ voxel,
    float* __restrict__ out,
    int N)
{
    const float SH_C0 = 0.28209479177387814f;
    const float SH_C1 = 0.4886025119029199f;
    const float C2_0 =  1.0925484305920792f;
    const float C2_1 = -1.0925484305920792f;
    const float C2_2 =  0.31539156525252005f;
    const float C2_3 = -1.0925484305920792f;
    const float C2_4 =  0.5462742152960396f;

    int i = blockIdx.x * blockDim.x + threadIdx.x;
    if (i >= N) return;

    // xs = x / SCALE  (IEEE divide to match reference compare semantics)
    float px = x[3 * i + 0] / 1.5f;
    float py = x[3 * i + 1] / 1.5f;
    float pz = x[3 * i + 2] / 1.5f;
    bool mask = (fabsf(px) < 0.5f) && (fabsf(py) < 0.5f) && (fabsf(pz) < 0.5f);

    float col0 = 0.0f, col1 = 0.0f, col2 = 0.0f, sig = 0.0f;

    if (mask) {
        const float step = 2.0f / (float)VNL;  // matches jnp 2.0/NL rounding
        float ix = fminf(fmaxf(px / step + (float)(VNL / 2), 0.0f), (float)(VNL - 1));
        float iy = fminf(fmaxf(py / step + (float)(VNL / 2), 0.0f), (float)(VNL - 1));
        float iz = fminf(fmaxf(pz / step + (float)(VNL / 2), 0.0f), (float)(VNL - 1));

        float fx = floorf(ix), fy = floorf(iy), fz = floorf(iz);
        int f0 = (int)fx, f1 = (int)fy, f2 = (int)fz;
        int c0 = (int)ceilf(ix), c1 = (int)ceilf(iy), c2 = (int)ceilf(iz);

        float t0 = ix - fx, t1 = iy - fy, t2 = iz - fz;
        float u0 = 1.0f - t0, u1 = 1.0f - t1, u2 = 1.0f - t2;

        // EXACT reference corner order and (non-standard) weight pairing:
        float w[8]  = { u2*u1*u0, u2*u1*t0, u2*t1*u0, u2*t1*t0,
                        t2*u1*u0, t2*u1*t0, t2*t1*u0, t2*t1*t0 };
        int  cx[8]  = { f0, c0, f0, f0, f0, c0, c0, c0 };
        int  cy[8]  = { f1, f1, c1, f1, c1, f1, c1, c1 };
        int  cz[8]  = { f2, f2, f2, c2, c2, c2, f2, c2 };

        float feat[28];
        #pragma unroll
        for (int c = 0; c < 28; ++c) feat[c] = 0.0f;

        #pragma unroll
        for (int j = 0; j < 8; ++j) {
            size_t base = ((size_t)(cx[j] * VNL + cy[j]) * VNL + cz[j]) * 28;
            const float4* vp = reinterpret_cast<const float4*>(voxel + base); // 112B cells -> 16B aligned
            float wj = w[j];
            #pragma unroll
            for (int q = 0; q < 7; ++q) {
                float4 v4 = vp[q];
                feat[4 * q + 0] += wj * v4.x;
                feat[4 * q + 1] += wj * v4.y;
                feat[4 * q + 2] += wj * v4.z;
                feat[4 * q + 3] += wj * v4.w;
            }
        }

        sig = fmaxf(feat[0], 0.0f);

        float dx = d[3 * i + 0], dy = d[3 * i + 1], dz = d[3 * i + 2];
        float xy = dx * dy, yz = dy * dz, xz = dx * dz;
        float zsq = 2.0f * dz * dz - dx * dx - dy * dy;
        float xmy = dx * dx - dy * dy;

        float cols[3];
        #pragma unroll
        for (int ch = 0; ch < 3; ++ch) {
            const int b = 1 + 9 * ch;  // compile-time after unroll
            cols[ch] = SH_C0 * feat[b + 0]
                     - SH_C1 * dy * feat[b + 1]
                     + SH_C1 * dz * feat[b + 2]
                     - SH_C1 * dx * feat[b + 3]
                     + C2_0 * xy  * feat[b + 4]
                     + C2_1 * yz  * feat[b + 5]
                     + C2_2 * zsq * feat[b + 6]
                     + C2_3 * xz  * feat[b + 7]
                     + C2_4 * xmy * feat[b + 8];
        }
        col0 = cols[0]; col1 = cols[1]; col2 = cols[2];
    }

    // Always write (masked-out points must be zero; harness poisons d_out).
    out[3 * i + 0] = col0;
    out[3 * i + 1] = col1;
    out[3 * i + 2] = col2;
    out[(size_t)3 * N + i] = sig;
}

extern "C" void kernel_launch(void* const* d_in, const int* in_sizes, int n_in,
                              void* d_out, int out_size, void* d_ws, size_t ws_size,
                              hipStream_t stream) {
    const float* x     = (const float*)d_in[0];
    const float* d     = (const float*)d_in[1];
    const float* voxel = (const float*)d_in[2];
    float* out = (float*)d_out;
    int N = in_sizes[0] / 3;

    int block = 256;
    int grid = (N + block - 1) / block;
    plenoxels_kernel<<<grid, block, 0, stream>>>(x, d, voxel, out, N);
}